// Round 12
// baseline (691.036 us; speedup 1.0000x reference)
//
#include <hip/hip_runtime.h>
#include <hip/hip_bf16.h>

// ---------------- problem constants ----------------
#define T_TOK 512
#define HD    2048   // hidden
#define ID    1024   // moe intermediate
#define NE    32     // routed experts
#define TOPK  8
#define NGRP  8
#define TGRP  4
#define NSH   2
#define SCALE 2.5f
#define NEXP  (NE + NSH)
#define KT1   64     // HD/32
#define KT2   32     // ID/32

typedef __attribute__((ext_vector_type(8))) short bf16x8;
typedef __attribute__((ext_vector_type(4))) float f32x4;
typedef unsigned short u16;
typedef unsigned long long u64;
typedef unsigned int u32;

__device__ __forceinline__ u16 f2bf(float f) {
    union { float f; u32 u; } a; a.f = f;
    u32 r = a.u + 0x7FFFu + ((a.u >> 16) & 1u);   // RNE
    return (u16)(r >> 16);
}

// pack two fp32 -> dword of 2 bf16 (lo in low half), RNE
__device__ __forceinline__ u32 pk2(float lo, float hi) {
    union { float f; u32 u; } a, b; a.f = lo; b.f = hi;
    u32 rl = a.u + 0x7FFFu + ((a.u >> 16) & 1u);
    u32 rh = b.u + 0x7FFFu + ((b.u >> 16) & 1u);
    return (rh & 0xFFFF0000u) | (rl >> 16);
}

__device__ __forceinline__ f32x4 mfma16(bf16x8 a, bf16x8 b, f32x4 c) {
    return __builtin_amdgcn_mfma_f32_16x16x32_bf16(a, b, c, 0, 0, 0);
}

union Q { uint4 q; bf16x8 v; };

// async global->LDS, 16B per lane
__device__ __forceinline__ void glds16(const void* g, void* l) {
    __builtin_amdgcn_global_load_lds(
        (const __attribute__((address_space(1))) u32*)g,
        (__attribute__((address_space(3))) u32*)l, 16, 0, 0);
}

// build B fragment from swizzled fp32 LDS tile [32k][128c] (verified r6-r11)
__device__ __forceinline__ bf16x8 bfrag(const float* Bt, int c, int g) {
    const int clo = c ^ (g << 4);
    const float* p_lo = Bt + g * 512 + clo;               // k = 4g + {0..3}
    const float* p_hi = Bt + g * 512 + 2048 + (clo ^ 64); // k = 4g+16+{0..3}
    union { u32 d[4]; bf16x8 v; } r;
    r.d[0] = pk2(p_lo[0],   p_lo[128]);
    r.d[1] = pk2(p_lo[256], p_lo[384]);
    r.d[2] = pk2(p_hi[0],   p_hi[128]);
    r.d[3] = pk2(p_hi[256], p_hi[384]);
    return r.v;
}

// ---------------- x -> bf16, frag-permuted rows (verified r4-r11) ---------
__global__ __launch_bounds__(256) void k_xconv(const float* __restrict__ x,
                                               u16* __restrict__ xb) {
    int gt = blockIdx.x * 256 + threadIdx.x;
    const float* s = x + (size_t)(gt >> 6) * HD + (gt & 63) * 32;
    float v[32];
#pragma unroll
    for (int i = 0; i < 8; i++) {
        float4 f = *(const float4*)(s + i * 4);
        v[i*4] = f.x; v[i*4+1] = f.y; v[i*4+2] = f.z; v[i*4+3] = f.w;
    }
    union { u16 o[32]; uint4 q[4]; } pk;
#pragma unroll
    for (int g = 0; g < 4; g++)
#pragma unroll
        for (int jj = 0; jj < 8; jj++) {
            int r = (jj < 4) ? 4*g + jj : 4*g + 16 + (jj - 4);
            pk.o[g*8 + jj] = f2bf(v[r]);
        }
    uint4* d = (uint4*)(xb + (size_t)gt * 32);
#pragma unroll
    for (int i = 0; i < 4; i++) d[i] = pk.q[i];
}

// ---------------- routing (verified; + slotmap for combine) ----------------
__global__ __launch_bounds__(64) void k_route(const float* __restrict__ x,
                                              const float* __restrict__ gw,
                                              const float* __restrict__ gb,
                                              int* __restrict__ counts,
                                              int* __restrict__ tok_ids,
                                              float* __restrict__ tok_w,
                                              int* __restrict__ slotmap) {
    const int t = blockIdx.x, lane = threadIdx.x;
    __shared__ float xr[HD];
    __shared__ float slog[NE], ss[NE], scb[NE], smm[NE];
    for (int i = lane; i < HD; i += 64) xr[i] = x[(size_t)t * HD + i];
    __syncthreads();
    const int e = lane >> 1, half = lane & 1;
    const float4* w4 = (const float4*)(gw + (size_t)e * HD + half * 1024);
    const float4* x4 = (const float4*)(xr + half * 1024);
    float acc = 0.f;
#pragma unroll 8
    for (int i = 0; i < 256; i++) {
        float4 a = x4[i], b = w4[i];
        acc += a.x * b.x + a.y * b.y + a.z * b.z + a.w * b.w;
    }
    acc += __shfl_xor(acc, 1, 64);
    if (!half) slog[e] = acc;
    __syncthreads();
    if (lane == 0) {
        for (int i = 0; i < NE; i++) {
            float s = 1.f / (1.f + __expf(-slog[i]));
            ss[i] = s; scb[i] = s + gb[i];
        }
        float gsc[NGRP];
        for (int g = 0; g < NGRP; g++) {
            float a = scb[4*g], b = scb[4*g+1], c = scb[4*g+2], d = scb[4*g+3];
            float mab = fmaxf(a,b), nab = fminf(a,b), mcd = fmaxf(c,d), ncd = fminf(c,d);
            float m2 = (mab >= mcd) ? fmaxf(nab, mcd) : fmaxf(ncd, mab);
            gsc[g] = fmaxf(mab, mcd) + m2;
        }
        int gmask = 0;
        for (int it = 0; it < TGRP; it++) {
            float best = -1e30f; int bi = 0;
            for (int g = 0; g < NGRP; g++)
                if (!((gmask >> g) & 1) && gsc[g] > best) { best = gsc[g]; bi = g; }
            gmask |= 1 << bi;
        }
        for (int i = 0; i < NE; i++)
            smm[i] = ((gmask >> (i >> 2)) & 1) ? scb[i] : -1e30f;
        int ids[TOPK]; float wv[TOPK]; float wsum = 0.f;
        for (int k = 0; k < TOPK; k++) {
            float best = -1e31f; int bi = 0;
            for (int i = 0; i < NE; i++)
                if (smm[i] > best) { best = smm[i]; bi = i; }
            smm[bi] = -1e32f;
            ids[k] = bi; wv[k] = ss[bi]; wsum += ss[bi];
        }
        float inv = SCALE / wsum;
        for (int k = 0; k < TOPK; k++) {
            int ee = ids[k];
            int pos = atomicAdd(&counts[ee], 1);
            tok_ids[ee * T_TOK + pos] = t;
            tok_w[ee * T_TOK + pos] = wv[k] * inv;
            slotmap[t * TOPK + k] = (ee << 9) | pos;
        }
    }
}

__global__ void k_scan(const int* __restrict__ counts, int* __restrict__ offs) {
    if (threadIdx.x == 0) {
        int o = 0;
        for (int e = 0; e < NE; e++) { offs[e] = o; o += counts[e]; }
    }
}

// ---- gate_up: A-direct registers + B 3-buffer glds, 2-step-ahead vmcnt ----
__global__ __launch_bounds__(256, 3) void k_gemm1(
    const float* __restrict__ wgu, const float* __restrict__ wsgu,
    const u16* __restrict__ xb,
    const int* __restrict__ counts, const int* __restrict__ offs,
    const int* __restrict__ tok_ids, const float* __restrict__ tok_w,
    u16* __restrict__ act) {
    const int tid = threadIdx.x, lane = tid & 63, w = tid >> 6;
    const int nb = blockIdx.x, mt = blockIdx.y, e = blockIdx.z;
    int ne, base, NS, upo; const float* gp;
    if (e < NE) {
        ne = counts[e]; base = offs[e];
        gp = wgu + (size_t)e * (HD * 2 * ID) + nb * 64;
        NS = 2 * ID; upo = ID;
    } else {
        int s = e - NE; ne = T_TOK; base = T_TOK * TOPK + s * T_TOK;
        gp = wsgu + s * ID + nb * 64;
        NS = 2 * NSH * ID; upo = NSH * ID;
    }
    if (mt * 128 >= ne) return;

    __shared__ __align__(16) float Bl[3][4096];   // 16 KB x3 (B only)

    // A: per-lane fragment base offsets into frag-permuted xb (8 row-chunks)
    const char* xbp = (const char*)xb;
    u32 aoff[8];
#pragma unroll
    for (int f = 0; f < 8; f++) {
        int sl = mt*128 + f*16 + (lane & 15);
        if (sl > ne-1) sl = ne-1;
        int tk = (e < NE) ? tok_ids[e*T_TOK + sl] : sl;
        aoff[f] = (u32)tk * (HD*2) + (lane >> 4) * 16;
    }

    const float* bsrc[4];
#pragma unroll
    for (int i = 0; i < 4; i++) {
        int kloc = 8*w + 2*i + (lane >> 5);
        int c4 = (4 * (lane & 31)) ^ (((kloc >> 2) & 7) << 4);
        const float* bp = (c4 < 64) ? (gp + c4) : (gp + upo + (c4 - 64));
        bsrc[i] = bp + (size_t)kloc * NS;
    }
    const size_t kstep = (size_t)32 * NS;

    auto stage = [&](int buf, int kt) {   // 4 glds per wave (B only)
#pragma unroll
        for (int i = 0; i < 4; i++)
            glds16(bsrc[i] + (size_t)kt * kstep, &Bl[buf][(8*w + 2*i) * 128]);
    };

    f32x4 accg[8], accu[8];
#pragma unroll
    for (int f = 0; f < 8; f++) {
        accg[f] = (f32x4){0.f,0.f,0.f,0.f};
        accu[f] = (f32x4){0.f,0.f,0.f,0.f};
    }

    const int cg = w * 16 + (lane & 15);   // gate tile-col 0..63
    const int g  = lane >> 4;

    stage(0, 0);
    stage(1, 1);
    for (int kt = 0; kt < KT1; kt++) {
        const int buf = kt % 3;
        if (kt + 2 < KT1) {
            stage((kt + 2) % 3, kt + 2);                  // 2-deep prefetch
            asm volatile("s_waitcnt vmcnt(8)" ::: "memory");  // tile kt landed
        } else if (kt + 1 < KT1) {
            asm volatile("s_waitcnt vmcnt(4)" ::: "memory");
        } else {
            asm volatile("s_waitcnt vmcnt(0)" ::: "memory");
        }
        __builtin_amdgcn_s_barrier();                     // tile kt landed (all waves)
        Q qg, qu;
        qg.v = bfrag(Bl[buf], cg, g);
        qu.v = bfrag(Bl[buf], cg + 64, g);
        const u32 ko = (u32)kt * 64;
#pragma unroll
        for (int f = 0; f < 8; f++) {
            Q qa;
            qa.q = *(const uint4*)(xbp + aoff[f] + ko);   // A direct (L2-hot)
            accg[f] = mfma16(qa.v, qg.v, accg[f]);
            accu[f] = mfma16(qa.v, qu.v, accu[f]);
        }
        __builtin_amdgcn_s_barrier();                     // reads done before re-stage
    }

    // epilogue: silu(g)*u*cw -> frag-permuted act rows
    const int icol = nb * 64 + w * 16 + (lane & 15);
    const int kt2 = icol >> 5, r = icol & 31;
    const int pos = kt2 * 32 + ((r & 16) ? (((r & 15) >> 2) * 8 + 4 + (r & 3))
                                         : ((r >> 2) * 8 + (r & 3)));
#pragma unroll
    for (int f = 0; f < 8; f++) {
#pragma unroll
        for (int j = 0; j < 4; j++) {
            int slot = mt * 128 + f * 16 + (lane >> 4) * 4 + j;
            if (slot < ne) {
                float cw = (e < NE) ? tok_w[e * T_TOK + slot] : 1.f;
                float gg = accg[f][j], uu = accu[f][j];
                float vv = gg / (1.f + __expf(-gg)) * uu * cw;
                act[(size_t)(base + slot) * ID + pos] = f2bf(vv);
            }
        }
    }
}

// ---- down-proj: A-direct + B 3-buffer glds, plain partial stores ----------
__global__ __launch_bounds__(256, 3) void k_gemm2(
    const float* __restrict__ wd, const float* __restrict__ wsd,
    const u16* __restrict__ act,
    const int* __restrict__ counts, const int* __restrict__ offs,
    float* __restrict__ part) {
    const int tid = threadIdx.x, lane = tid & 63, w = tid >> 6;
    const int nb = blockIdx.x, mt = blockIdx.y, e = blockIdx.z;
    int ne, base; const float* gp;
    if (e < NE) {
        ne = counts[e]; base = offs[e];
        gp = wd + (size_t)e * (ID * HD) + nb * 128;
    } else {
        int s = e - NE; ne = T_TOK; base = T_TOK * TOPK + s * T_TOK;
        gp = wsd + (size_t)s * (ID * HD) + nb * 128;
    }
    if (mt * 128 >= ne) return;
    const int NS = HD;

    __shared__ __align__(16) float Bl[3][4096];

    const char* ap = (const char*)act;
    u32 aoff[8];
#pragma unroll
    for (int f = 0; f < 8; f++) {
        int sl = mt*128 + f*16 + (lane & 15);
        if (sl > ne-1) sl = ne-1;
        aoff[f] = (u32)(base + sl) * (ID*2) + (lane >> 4) * 16;
    }

    const float* bsrc[4];
#pragma unroll
    for (int i = 0; i < 4; i++) {
        int kloc = 8*w + 2*i + (lane >> 5);
        int c4 = (4 * (lane & 31)) ^ (((kloc >> 2) & 7) << 4);
        bsrc[i] = gp + (size_t)kloc * NS + c4;
    }
    const size_t kstep = (size_t)32 * NS;

    auto stage = [&](int buf, int kt) {   // 4 glds per wave
#pragma unroll
        for (int i = 0; i < 4; i++)
            glds16(bsrc[i] + (size_t)kt * kstep, &Bl[buf][(8*w + 2*i) * 128]);
    };

    f32x4 acc[8][2];
#pragma unroll
    for (int f = 0; f < 8; f++) {
        acc[f][0] = (f32x4){0.f,0.f,0.f,0.f};
        acc[f][1] = (f32x4){0.f,0.f,0.f,0.f};
    }

    const int cA = w * 16 + (lane & 15);
    const int g  = lane >> 4;

    stage(0, 0);
    stage(1, 1);
    for (int kt = 0; kt < KT2; kt++) {
        const int buf = kt % 3;
        if (kt + 2 < KT2) {
            stage((kt + 2) % 3, kt + 2);
            asm volatile("s_waitcnt vmcnt(8)" ::: "memory");
        } else if (kt + 1 < KT2) {
            asm volatile("s_waitcnt vmcnt(4)" ::: "memory");
        } else {
            asm volatile("s_waitcnt vmcnt(0)" ::: "memory");
        }
        __builtin_amdgcn_s_barrier();
        Q q0, q1;
        q0.v = bfrag(Bl[buf], cA, g);
        q1.v = bfrag(Bl[buf], cA + 64, g);
        const u32 ko = (u32)kt * 64;
#pragma unroll
        for (int f = 0; f < 8; f++) {
            Q qa;
            qa.q = *(const uint4*)(ap + aoff[f] + ko);
            acc[f][0] = mfma16(qa.v, q0.v, acc[f][0]);
            acc[f][1] = mfma16(qa.v, q1.v, acc[f][1]);
        }
        __builtin_amdgcn_s_barrier();
    }

    const int col0 = nb * 128 + w * 16 + (lane & 15);
#pragma unroll
    for (int f = 0; f < 8; f++) {
#pragma unroll
        for (int j = 0; j < 4; j++) {
            int slot = mt * 128 + f * 16 + (lane >> 4) * 4 + j;
            if (slot < ne) {
                float* pr = part + (size_t)(base + slot) * HD + col0;
                pr[0]  = acc[f][0][j];
                pr[64] = acc[f][1][j];
            }
        }
    }
}

// ---------------- combine: out[t] = sum of 8 routed + 2 shared partials ----
__global__ __launch_bounds__(256) void k_combine(const float* __restrict__ part,
                                                 const int* __restrict__ offs,
                                                 const int* __restrict__ slotmap,
                                                 float* __restrict__ out) {
    const int t = blockIdx.x, tid = threadIdx.x;
    __shared__ int rows[16];
    if (tid < TOPK) {
        int pk = slotmap[t * TOPK + tid];
        rows[tid] = offs[pk >> 9] + (pk & 511);
    } else if (tid < TOPK + NSH) {
        rows[tid] = T_TOK * TOPK + (tid - TOPK) * T_TOK + t;
    }
    __syncthreads();
    float4 s0 = {0,0,0,0}, s1 = {0,0,0,0};
#pragma unroll
    for (int k = 0; k < TOPK + NSH; k++) {
        const float* p = part + (size_t)rows[k] * HD + tid * 8;
        float4 a = ((const float4*)p)[0], b = ((const float4*)p)[1];
        s0.x += a.x; s0.y += a.y; s0.z += a.z; s0.w += a.w;
        s1.x += b.x; s1.y += b.y; s1.z += b.z; s1.w += b.w;
    }
    float* o = out + (size_t)t * HD + tid * 8;
    ((float4*)o)[0] = s0;
    ((float4*)o)[1] = s1;
}

// ---------------- launcher ----------------
extern "C" void kernel_launch(void* const* d_in, const int* in_sizes, int n_in,
                              void* d_out, int out_size, void* d_ws, size_t ws_size,
                              hipStream_t stream) {
    const float* x    = (const float*)d_in[0];
    const float* gw   = (const float*)d_in[1];
    const float* gb   = (const float*)d_in[2];
    const float* wgu  = (const float*)d_in[3];
    const float* wd   = (const float*)d_in[4];
    const float* wsgu = (const float*)d_in[5];
    const float* wsd  = (const float*)d_in[6];
    float* out = (float*)d_out;

    char* wsb = (char*)d_ws;
    int*   counts  = (int*)(wsb);                  // 128 B
    int*   offs    = (int*)(wsb + 128);            // 128 B
    int*   tok_ids = (int*)(wsb + 256);            // 64 KB
    float* tok_w   = (float*)(wsb + 65792);        // 64 KB
    int*   slotmap = (int*)(wsb + 131328);         // 16 KB
    u16*   xb      = (u16*)(wsb + 147712);         // 2 MB (frag-permuted)
    u16*   act     = (u16*)(wsb + 2244864);        // 10 MB (frag-permuted)
    float* part    = (float*)(wsb + 12730624);     // 40 MB (5120 x 2048 fp32)

    hipMemsetAsync(counts, 0, 128, stream);
    k_xconv<<<dim3((T_TOK * 64) / 256), 256, 0, stream>>>(x, xb);
    k_route<<<dim3(T_TOK), 64, 0, stream>>>(x, gw, gb, counts, tok_ids, tok_w, slotmap);
    k_scan<<<dim3(1), 64, 0, stream>>>(counts, offs);
    k_gemm1<<<dim3(ID / 64, 4, NEXP), 256, 0, stream>>>(
        wgu, wsgu, xb, counts, offs, tok_ids, tok_w, act);
    k_gemm2<<<dim3(HD / 128, 4, NEXP), 256, 0, stream>>>(
        wd, wsd, act, counts, offs, part);
    k_combine<<<dim3(T_TOK), 256, 0, stream>>>(part, offs, slotmap, out);
}

// Round 13
// 425.545 us; speedup vs baseline: 1.6239x; 1.6239x over previous
//
#include <hip/hip_runtime.h>
#include <hip/hip_bf16.h>

// ---------------- problem constants ----------------
#define T_TOK 512
#define HD    2048   // hidden
#define ID    1024   // moe intermediate
#define NE    32     // routed experts
#define TOPK  8
#define NGRP  8
#define TGRP  4
#define NSH   2
#define SCALE 2.5f
#define NEXP  (NE + NSH)
#define KT1   64     // HD/32
#define KT2   32     // ID/32
#define NSLOT (T_TOK * TOPK + NSH * T_TOK)   // 5120

typedef __attribute__((ext_vector_type(8))) short bf16x8;
typedef __attribute__((ext_vector_type(4))) float f32x4;
typedef unsigned short u16;
typedef unsigned long long u64;
typedef unsigned int u32;

__device__ __forceinline__ u16 f2bf(float f) {
    union { float f; u32 u; } a; a.f = f;
    u32 r = a.u + 0x7FFFu + ((a.u >> 16) & 1u);   // RNE
    return (u16)(r >> 16);
}

__device__ __forceinline__ float bf2f(u16 h) {
    union { u32 u; float f; } z; z.u = (u32)h << 16; return z.f;
}

// pack two fp32 -> dword of 2 bf16 (lo in low half), RNE
__device__ __forceinline__ u32 pk2(float lo, float hi) {
    union { float f; u32 u; } a, b; a.f = lo; b.f = hi;
    u32 rl = a.u + 0x7FFFu + ((a.u >> 16) & 1u);
    u32 rh = b.u + 0x7FFFu + ((b.u >> 16) & 1u);
    return (rh & 0xFFFF0000u) | (rl >> 16);
}

__device__ __forceinline__ f32x4 mfma16(bf16x8 a, bf16x8 b, f32x4 c) {
    return __builtin_amdgcn_mfma_f32_16x16x32_bf16(a, b, c, 0, 0, 0);
}

union Q { uint4 q; bf16x8 v; };

// async global->LDS, 16B per lane
__device__ __forceinline__ void glds16(const void* g, void* l) {
    __builtin_amdgcn_global_load_lds(
        (const __attribute__((address_space(1))) u32*)g,
        (__attribute__((address_space(3))) u32*)l, 16, 0, 0);
}

// build B fragment from swizzled fp32 LDS tile [32k][128c] (verified r6-r12)
__device__ __forceinline__ bf16x8 bfrag(const float* Bt, int c, int g) {
    const int clo = c ^ (g << 4);
    const float* p_lo = Bt + g * 512 + clo;               // k = 4g + {0..3}
    const float* p_hi = Bt + g * 512 + 2048 + (clo ^ 64); // k = 4g+16+{0..3}
    union { u32 d[4]; bf16x8 v; } r;
    r.d[0] = pk2(p_lo[0],   p_lo[128]);
    r.d[1] = pk2(p_lo[256], p_lo[384]);
    r.d[2] = pk2(p_hi[0],   p_hi[128]);
    r.d[3] = pk2(p_hi[256], p_hi[384]);
    return r.v;
}

// ---------------- x -> bf16, frag-permuted rows (verified r4-r12) ---------
__global__ __launch_bounds__(256) void k_xconv(const float* __restrict__ x,
                                               u16* __restrict__ xb) {
    int gt = blockIdx.x * 256 + threadIdx.x;
    const float* s = x + (size_t)(gt >> 6) * HD + (gt & 63) * 32;
    float v[32];
#pragma unroll
    for (int i = 0; i < 8; i++) {
        float4 f = *(const float4*)(s + i * 4);
        v[i*4] = f.x; v[i*4+1] = f.y; v[i*4+2] = f.z; v[i*4+3] = f.w;
    }
    union { u16 o[32]; uint4 q[4]; } pk;
#pragma unroll
    for (int g = 0; g < 4; g++)
#pragma unroll
        for (int jj = 0; jj < 8; jj++) {
            int r = (jj < 4) ? 4*g + jj : 4*g + 16 + (jj - 4);
            pk.o[g*8 + jj] = f2bf(v[r]);
        }
    uint4* d = (uint4*)(xb + (size_t)gt * 32);
#pragma unroll
    for (int i = 0; i < 4; i++) d[i] = pk.q[i];
}

// ---------------- routing (verified; + slotmap for combine) ----------------
__global__ __launch_bounds__(64) void k_route(const float* __restrict__ x,
                                              const float* __restrict__ gw,
                                              const float* __restrict__ gb,
                                              int* __restrict__ counts,
                                              int* __restrict__ tok_ids,
                                              float* __restrict__ tok_w,
                                              int* __restrict__ slotmap) {
    const int t = blockIdx.x, lane = threadIdx.x;
    __shared__ float xr[HD];
    __shared__ float slog[NE], ss[NE], scb[NE], smm[NE];
    for (int i = lane; i < HD; i += 64) xr[i] = x[(size_t)t * HD + i];
    __syncthreads();
    const int e = lane >> 1, half = lane & 1;
    const float4* w4 = (const float4*)(gw + (size_t)e * HD + half * 1024);
    const float4* x4 = (const float4*)(xr + half * 1024);
    float acc = 0.f;
#pragma unroll 8
    for (int i = 0; i < 256; i++) {
        float4 a = x4[i], b = w4[i];
        acc += a.x * b.x + a.y * b.y + a.z * b.z + a.w * b.w;
    }
    acc += __shfl_xor(acc, 1, 64);
    if (!half) slog[e] = acc;
    __syncthreads();
    if (lane == 0) {
        for (int i = 0; i < NE; i++) {
            float s = 1.f / (1.f + __expf(-slog[i]));
            ss[i] = s; scb[i] = s + gb[i];
        }
        float gsc[NGRP];
        for (int g = 0; g < NGRP; g++) {
            float a = scb[4*g], b = scb[4*g+1], c = scb[4*g+2], d = scb[4*g+3];
            float mab = fmaxf(a,b), nab = fminf(a,b), mcd = fmaxf(c,d), ncd = fminf(c,d);
            float m2 = (mab >= mcd) ? fmaxf(nab, mcd) : fmaxf(ncd, mab);
            gsc[g] = fmaxf(mab, mcd) + m2;
        }
        int gmask = 0;
        for (int it = 0; it < TGRP; it++) {
            float best = -1e30f; int bi = 0;
            for (int g = 0; g < NGRP; g++)
                if (!((gmask >> g) & 1) && gsc[g] > best) { best = gsc[g]; bi = g; }
            gmask |= 1 << bi;
        }
        for (int i = 0; i < NE; i++)
            smm[i] = ((gmask >> (i >> 2)) & 1) ? scb[i] : -1e30f;
        int ids[TOPK]; float wv[TOPK]; float wsum = 0.f;
        for (int k = 0; k < TOPK; k++) {
            float best = -1e31f; int bi = 0;
            for (int i = 0; i < NE; i++)
                if (smm[i] > best) { best = smm[i]; bi = i; }
            smm[bi] = -1e32f;
            ids[k] = bi; wv[k] = ss[bi]; wsum += ss[bi];
        }
        float inv = SCALE / wsum;
        for (int k = 0; k < TOPK; k++) {
            int ee = ids[k];
            int pos = atomicAdd(&counts[ee], 1);
            tok_ids[ee * T_TOK + pos] = t;
            tok_w[ee * T_TOK + pos] = wv[k] * inv;
            slotmap[t * TOPK + k] = (ee << 9) | pos;
        }
    }
}

// offs prefix-scan + flat per-slot combine-weight table
__global__ __launch_bounds__(256) void k_finalize(const int* __restrict__ counts,
                                                  int* __restrict__ offs,
                                                  const float* __restrict__ tok_w,
                                                  float* __restrict__ cwflat) {
    __shared__ int so[NE];
    if (threadIdx.x == 0) {
        int o = 0;
        for (int e = 0; e < NE; e++) { offs[e] = o; so[e] = o; o += counts[e]; }
    }
    __syncthreads();
    for (int e = 0; e < NE; e++) {
        int ne = counts[e], b = so[e];
        for (int i = threadIdx.x; i < ne; i += 256)
            cwflat[b + i] = tok_w[e * T_TOK + i];
    }
    for (int i = T_TOK * TOPK + threadIdx.x; i < NSLOT; i += 256)
        cwflat[i] = 1.f;
}

// ---- gate_up RAW: BN=128 contiguous gu-cols, bf16 product out (no silu) ----
// Structural clone of k_gemm2 (512B B-segments); nb<8 = gate cols, nb>=8 = up.
__global__ __launch_bounds__(256, 3) void k_gemm1(
    const float* __restrict__ wgu, const float* __restrict__ wsgu,
    const u16* __restrict__ xb,
    const int* __restrict__ counts, const int* __restrict__ offs,
    const int* __restrict__ tok_ids,
    u16* __restrict__ gu) {
    const int tid = threadIdx.x, lane = tid & 63, w = tid >> 6;
    const int nb = blockIdx.x, mt = blockIdx.y, e = blockIdx.z;
    int ne, base, NS; const float* gp;
    const int cb = nb * 128;
    if (e < NE) {
        ne = counts[e]; base = offs[e];
        gp = wgu + (size_t)e * (HD * 2 * ID) + cb;
        NS = 2 * ID;
    } else {
        int s = e - NE; ne = T_TOK; base = T_TOK * TOPK + s * T_TOK;
        gp = wsgu + ((cb < ID) ? (s * ID + cb) : (NSH * ID + s * ID + (cb - ID)));
        NS = 2 * NSH * ID;
    }
    if (mt * 128 >= ne) return;

    __shared__ __align__(16) u16   Al[2][4096];   // 8 KB x2
    __shared__ __align__(16) float Bl[2][4096];   // 16 KB x2

    const int c0 = 2 * w, c1 = 2 * w + 1;
    int sl0 = mt*128 + c0*16 + (lane & 15); if (sl0 > ne-1) sl0 = ne-1;
    int sl1 = mt*128 + c1*16 + (lane & 15); if (sl1 > ne-1) sl1 = ne-1;
    const int t0 = (e < NE) ? tok_ids[e*T_TOK + sl0] : sl0;
    const int t1 = (e < NE) ? tok_ids[e*T_TOK + sl1] : sl1;
    const char* a0 = (const char*)xb + (u32)t0 * (HD*2) + (lane >> 4) * 16;
    const char* a1 = (const char*)xb + (u32)t1 * (HD*2) + (lane >> 4) * 16;

    const float* bsrc[4];
#pragma unroll
    for (int i = 0; i < 4; i++) {
        int kloc = 8*w + 2*i + (lane >> 5);
        int c4 = (4 * (lane & 31)) ^ (((kloc >> 2) & 7) << 4);
        bsrc[i] = gp + (size_t)kloc * NS + c4;
    }
    const size_t kstep = (size_t)32 * NS;

    auto stage = [&](int buf, int kt) {   // 6 glds per wave
        glds16(a0 + (u32)kt * 64, &Al[buf][c0 * 512]);
        glds16(a1 + (u32)kt * 64, &Al[buf][c1 * 512]);
#pragma unroll
        for (int i = 0; i < 4; i++)
            glds16(bsrc[i] + (size_t)kt * kstep, &Bl[buf][(8*w + 2*i) * 128]);
    };

    f32x4 acc[8][2];
#pragma unroll
    for (int f = 0; f < 8; f++) {
        acc[f][0] = (f32x4){0.f,0.f,0.f,0.f};
        acc[f][1] = (f32x4){0.f,0.f,0.f,0.f};
    }

    const int cA = w * 16 + (lane & 15);
    const int g  = lane >> 4;

    stage(0, 0);
    int buf = 0;
    for (int kt = 0; kt < KT1; kt++) {
        if (kt + 1 < KT1) {
            stage(buf ^ 1, kt + 1);                       // prefetch stays in flight
            asm volatile("s_waitcnt vmcnt(6)" ::: "memory");
        } else {
            asm volatile("s_waitcnt vmcnt(0)" ::: "memory");
        }
        __builtin_amdgcn_s_barrier();
        Q q0, q1;
        q0.v = bfrag(Bl[buf], cA, g);
        q1.v = bfrag(Bl[buf], cA + 64, g);
#pragma unroll
        for (int f = 0; f < 8; f++) {
            Q qa;
            qa.q = *(const uint4*)&Al[buf][f * 512 + (lane >> 4) * 128 + (lane & 15) * 8];
            acc[f][0] = mfma16(qa.v, q0.v, acc[f][0]);
            acc[f][1] = mfma16(qa.v, q1.v, acc[f][1]);
        }
        __builtin_amdgcn_s_barrier();
        buf ^= 1;
    }

    const int col0 = cb + w * 16 + (lane & 15);
#pragma unroll
    for (int f = 0; f < 8; f++) {
#pragma unroll
        for (int j = 0; j < 4; j++) {
            int slot = mt * 128 + f * 16 + (lane >> 4) * 4 + j;
            if (slot < ne) {
                u16* pr = gu + (size_t)(base + slot) * (2 * ID) + col0;
                pr[0]  = f2bf(acc[f][0][j]);
                pr[64] = f2bf(acc[f][1][j]);
            }
        }
    }
}

// ---- silu fuse: act[s][pos(c)] = silu(g)*u*cw, frag-permuted rows ----------
__global__ __launch_bounds__(256) void k_silu(const u16* __restrict__ gu,
                                              const float* __restrict__ cwflat,
                                              u16* __restrict__ act) {
    const int s = blockIdx.x, t = threadIdx.x;
    const float cw = cwflat[s];
    const int c0 = t * 4;
    const int kt2 = c0 >> 5, r0 = c0 & 31;
    const int pb = kt2 * 32 + ((r0 & 16) ? (((r0 & 15) >> 2) * 8 + 4) : ((r0 >> 2) * 8));
    const u16* gr = gu + (size_t)s * (2 * ID);
    union { u16 u[4]; u64 h; } g4, u4, o4;
    g4.h = *(const u64*)(gr + c0);
    u4.h = *(const u64*)(gr + ID + c0);
#pragma unroll
    for (int j = 0; j < 4; j++) {
        float gg = bf2f(g4.u[j]), uu = bf2f(u4.u[j]);
        float v = gg / (1.f + __expf(-gg)) * uu * cw;
        o4.u[j] = f2bf(v);
    }
    *(u64*)(act + (size_t)s * ID + pb) = o4.h;
}

// ---- down-proj: counted vmcnt, plain partial stores (r10 verbatim) --------
__global__ __launch_bounds__(256, 3) void k_gemm2(
    const float* __restrict__ wd, const float* __restrict__ wsd,
    const u16* __restrict__ act,
    const int* __restrict__ counts, const int* __restrict__ offs,
    float* __restrict__ part) {
    const int tid = threadIdx.x, lane = tid & 63, w = tid >> 6;
    const int nb = blockIdx.x, mt = blockIdx.y, e = blockIdx.z;
    int ne, base; const float* gp;
    if (e < NE) {
        ne = counts[e]; base = offs[e];
        gp = wd + (size_t)e * (ID * HD) + nb * 128;
    } else {
        int s = e - NE; ne = T_TOK; base = T_TOK * TOPK + s * T_TOK;
        gp = wsd + (size_t)s * (ID * HD) + nb * 128;
    }
    if (mt * 128 >= ne) return;
    const int NS = HD;

    __shared__ __align__(16) u16   Al[2][4096];
    __shared__ __align__(16) float Bl[2][4096];

    const int c0 = 2 * w, c1 = 2 * w + 1;
    int sl0 = mt*128 + c0*16 + (lane & 15); if (sl0 > ne-1) sl0 = ne-1;
    int sl1 = mt*128 + c1*16 + (lane & 15); if (sl1 > ne-1) sl1 = ne-1;
    const char* a0 = (const char*)act + (size_t)(base + sl0) * (ID*2) + (lane >> 4) * 16;
    const char* a1 = (const char*)act + (size_t)(base + sl1) * (ID*2) + (lane >> 4) * 16;

    const float* bsrc[4];
#pragma unroll
    for (int i = 0; i < 4; i++) {
        int kloc = 8*w + 2*i + (lane >> 5);
        int c4 = (4 * (lane & 31)) ^ (((kloc >> 2) & 7) << 4);
        bsrc[i] = gp + (size_t)kloc * NS + c4;
    }
    const size_t kstep = (size_t)32 * NS;

    auto stage = [&](int buf, int kt) {   // 6 glds per wave
        glds16(a0 + (u32)kt * 64, &Al[buf][c0 * 512]);
        glds16(a1 + (u32)kt * 64, &Al[buf][c1 * 512]);
#pragma unroll
        for (int i = 0; i < 4; i++)
            glds16(bsrc[i] + (size_t)kt * kstep, &Bl[buf][(8*w + 2*i) * 128]);
    };

    f32x4 acc[8][2];
#pragma unroll
    for (int f = 0; f < 8; f++) {
        acc[f][0] = (f32x4){0.f,0.f,0.f,0.f};
        acc[f][1] = (f32x4){0.f,0.f,0.f,0.f};
    }

    const int cA = w * 16 + (lane & 15);
    const int g  = lane >> 4;

    stage(0, 0);
    int buf = 0;
    for (int kt = 0; kt < KT2; kt++) {
        if (kt + 1 < KT2) {
            stage(buf ^ 1, kt + 1);
            asm volatile("s_waitcnt vmcnt(6)" ::: "memory");
        } else {
            asm volatile("s_waitcnt vmcnt(0)" ::: "memory");
        }
        __builtin_amdgcn_s_barrier();
        Q q0, q1;
        q0.v = bfrag(Bl[buf], cA, g);
        q1.v = bfrag(Bl[buf], cA + 64, g);
#pragma unroll
        for (int f = 0; f < 8; f++) {
            Q qa;
            qa.q = *(const uint4*)&Al[buf][f * 512 + (lane >> 4) * 128 + (lane & 15) * 8];
            acc[f][0] = mfma16(qa.v, q0.v, acc[f][0]);
            acc[f][1] = mfma16(qa.v, q1.v, acc[f][1]);
        }
        __builtin_amdgcn_s_barrier();
        buf ^= 1;
    }

    const int col0 = nb * 128 + w * 16 + (lane & 15);
#pragma unroll
    for (int f = 0; f < 8; f++) {
#pragma unroll
        for (int j = 0; j < 4; j++) {
            int slot = mt * 128 + f * 16 + (lane >> 4) * 4 + j;
            if (slot < ne) {
                float* pr = part + (size_t)(base + slot) * HD + col0;
                pr[0]  = acc[f][0][j];
                pr[64] = acc[f][1][j];
            }
        }
    }
}

// ---------------- combine: out[t] = sum of 8 routed + 2 shared partials ----
__global__ __launch_bounds__(256) void k_combine(const float* __restrict__ part,
                                                 const int* __restrict__ offs,
                                                 const int* __restrict__ slotmap,
                                                 float* __restrict__ out) {
    const int t = blockIdx.x, tid = threadIdx.x;
    __shared__ int rows[16];
    if (tid < TOPK) {
        int pk = slotmap[t * TOPK + tid];
        rows[tid] = offs[pk >> 9] + (pk & 511);
    } else if (tid < TOPK + NSH) {
        rows[tid] = T_TOK * TOPK + (tid - TOPK) * T_TOK + t;
    }
    __syncthreads();
    float4 s0 = {0,0,0,0}, s1 = {0,0,0,0};
#pragma unroll
    for (int k = 0; k < TOPK + NSH; k++) {
        const float* p = part + (size_t)rows[k] * HD + tid * 8;
        float4 a = ((const float4*)p)[0], b = ((const float4*)p)[1];
        s0.x += a.x; s0.y += a.y; s0.z += a.z; s0.w += a.w;
        s1.x += b.x; s1.y += b.y; s1.z += b.z; s1.w += b.w;
    }
    float* o = out + (size_t)t * HD + tid * 8;
    ((float4*)o)[0] = s0;
    ((float4*)o)[1] = s1;
}

// ---------------- launcher ----------------
extern "C" void kernel_launch(void* const* d_in, const int* in_sizes, int n_in,
                              void* d_out, int out_size, void* d_ws, size_t ws_size,
                              hipStream_t stream) {
    const float* x    = (const float*)d_in[0];
    const float* gw   = (const float*)d_in[1];
    const float* gb   = (const float*)d_in[2];
    const float* wgu  = (const float*)d_in[3];
    const float* wd   = (const float*)d_in[4];
    const float* wsgu = (const float*)d_in[5];
    const float* wsd  = (const float*)d_in[6];
    float* out = (float*)d_out;

    char* wsb = (char*)d_ws;
    int*   counts  = (int*)(wsb);                  // 128 B
    int*   offs    = (int*)(wsb + 128);            // 128 B
    int*   tok_ids = (int*)(wsb + 256);            // 64 KB
    float* tok_w   = (float*)(wsb + 65792);        // 64 KB
    int*   slotmap = (int*)(wsb + 131328);         // 16 KB
    float* cwflat  = (float*)(wsb + 147712);       // 20 KB (5120 f32)
    u16*   xb      = (u16*)(wsb + 168192);         // 2 MB (frag-permuted)
    u16*   act     = (u16*)(wsb + 2265344);        // 10 MB (frag-permuted)
    u16*   gu      = (u16*)(wsb + 12751104);       // 20 MB (5120 x 2048 bf16)
    float* part    = (float*)(wsb + 33722624);     // 40 MB (5120 x 2048 fp32)

    hipMemsetAsync(counts, 0, 128, stream);
    k_xconv<<<dim3((T_TOK * 64) / 256), 256, 0, stream>>>(x, xb);
    k_route<<<dim3(T_TOK), 64, 0, stream>>>(x, gw, gb, counts, tok_ids, tok_w, slotmap);
    k_finalize<<<dim3(1), 256, 0, stream>>>(counts, offs, tok_w, cwflat);
    k_gemm1<<<dim3(16, 4, NEXP), 256, 0, stream>>>(
        wgu, wsgu, xb, counts, offs, tok_ids, gu);
    k_silu<<<dim3(NSLOT), 256, 0, stream>>>(gu, cwflat, act);
    k_gemm2<<<dim3(HD / 128, 4, NEXP), 256, 0, stream>>>(
        wd, wsd, act, counts, offs, part);
    k_combine<<<dim3(T_TOK), 256, 0, stream>>>(part, offs, slotmap, out);
}

// Round 14
// 390.453 us; speedup vs baseline: 1.7698x; 1.0899x over previous
//
#include <hip/hip_runtime.h>
#include <hip/hip_bf16.h>

// ---------------- problem constants ----------------
#define T_TOK 512
#define HD    2048   // hidden
#define ID    1024   // moe intermediate
#define NE    32     // routed experts
#define TOPK  8
#define NGRP  8
#define TGRP  4
#define NSH   2
#define SCALE 2.5f
#define NEXP  (NE + NSH)
#define KT1   64     // HD/32
#define KT2   32     // ID/32

typedef __attribute__((ext_vector_type(8))) short bf16x8;
typedef __attribute__((ext_vector_type(4))) float f32x4;
typedef unsigned short u16;
typedef unsigned long long u64;
typedef unsigned int u32;

__device__ __forceinline__ u16 f2bf(float f) {
    union { float f; u32 u; } a; a.f = f;
    u32 r = a.u + 0x7FFFu + ((a.u >> 16) & 1u);   // RNE
    return (u16)(r >> 16);
}

// pack two fp32 -> dword of 2 bf16 (lo in low half), RNE
__device__ __forceinline__ u32 pk2(float lo, float hi) {
    union { float f; u32 u; } a, b; a.f = lo; b.f = hi;
    u32 rl = a.u + 0x7FFFu + ((a.u >> 16) & 1u);
    u32 rh = b.u + 0x7FFFu + ((b.u >> 16) & 1u);
    return (rh & 0xFFFF0000u) | (rl >> 16);
}

__device__ __forceinline__ f32x4 mfma16(bf16x8 a, bf16x8 b, f32x4 c) {
    return __builtin_amdgcn_mfma_f32_16x16x32_bf16(a, b, c, 0, 0, 0);
}

union Q { uint4 q; bf16x8 v; };

// async global->LDS, 16B per lane
__device__ __forceinline__ void glds16(const void* g, void* l) {
    __builtin_amdgcn_global_load_lds(
        (const __attribute__((address_space(1))) u32*)g,
        (__attribute__((address_space(3))) u32*)l, 16, 0, 0);
}

// build B fragment from swizzled fp32 LDS tile [32k][128c] (verified r6-r13)
__device__ __forceinline__ bf16x8 bfrag(const float* Bt, int c, int g) {
    const int clo = c ^ (g << 4);
    const float* p_lo = Bt + g * 512 + clo;               // k = 4g + {0..3}
    const float* p_hi = Bt + g * 512 + 2048 + (clo ^ 64); // k = 4g+16+{0..3}
    union { u32 d[4]; bf16x8 v; } r;
    r.d[0] = pk2(p_lo[0],   p_lo[128]);
    r.d[1] = pk2(p_lo[256], p_lo[384]);
    r.d[2] = pk2(p_hi[0],   p_hi[128]);
    r.d[3] = pk2(p_hi[256], p_hi[384]);
    return r.v;
}

// ---------------- x -> bf16, frag-permuted rows (verified r4-r13) ---------
__global__ __launch_bounds__(256) void k_xconv(const float* __restrict__ x,
                                               u16* __restrict__ xb) {
    int gt = blockIdx.x * 256 + threadIdx.x;
    const float* s = x + (size_t)(gt >> 6) * HD + (gt & 63) * 32;
    float v[32];
#pragma unroll
    for (int i = 0; i < 8; i++) {
        float4 f = *(const float4*)(s + i * 4);
        v[i*4] = f.x; v[i*4+1] = f.y; v[i*4+2] = f.z; v[i*4+3] = f.w;
    }
    union { u16 o[32]; uint4 q[4]; } pk;
#pragma unroll
    for (int g = 0; g < 4; g++)
#pragma unroll
        for (int jj = 0; jj < 8; jj++) {
            int r = (jj < 4) ? 4*g + jj : 4*g + 16 + (jj - 4);
            pk.o[g*8 + jj] = f2bf(v[r]);
        }
    uint4* d = (uint4*)(xb + (size_t)gt * 32);
#pragma unroll
    for (int i = 0; i < 4; i++) d[i] = pk.q[i];
}

// ---------------- routing (verified; + slotmap for combine) ----------------
__global__ __launch_bounds__(64) void k_route(const float* __restrict__ x,
                                              const float* __restrict__ gw,
                                              const float* __restrict__ gb,
                                              int* __restrict__ counts,
                                              int* __restrict__ tok_ids,
                                              float* __restrict__ tok_w,
                                              int* __restrict__ slotmap) {
    const int t = blockIdx.x, lane = threadIdx.x;
    __shared__ float xr[HD];
    __shared__ float slog[NE], ss[NE], scb[NE], smm[NE];
    for (int i = lane; i < HD; i += 64) xr[i] = x[(size_t)t * HD + i];
    __syncthreads();
    const int e = lane >> 1, half = lane & 1;
    const float4* w4 = (const float4*)(gw + (size_t)e * HD + half * 1024);
    const float4* x4 = (const float4*)(xr + half * 1024);
    float acc = 0.f;
#pragma unroll 8
    for (int i = 0; i < 256; i++) {
        float4 a = x4[i], b = w4[i];
        acc += a.x * b.x + a.y * b.y + a.z * b.z + a.w * b.w;
    }
    acc += __shfl_xor(acc, 1, 64);
    if (!half) slog[e] = acc;
    __syncthreads();
    if (lane == 0) {
        for (int i = 0; i < NE; i++) {
            float s = 1.f / (1.f + __expf(-slog[i]));
            ss[i] = s; scb[i] = s + gb[i];
        }
        float gsc[NGRP];
        for (int g = 0; g < NGRP; g++) {
            float a = scb[4*g], b = scb[4*g+1], c = scb[4*g+2], d = scb[4*g+3];
            float mab = fmaxf(a,b), nab = fminf(a,b), mcd = fmaxf(c,d), ncd = fminf(c,d);
            float m2 = (mab >= mcd) ? fmaxf(nab, mcd) : fmaxf(ncd, mab);
            gsc[g] = fmaxf(mab, mcd) + m2;
        }
        int gmask = 0;
        for (int it = 0; it < TGRP; it++) {
            float best = -1e30f; int bi = 0;
            for (int g = 0; g < NGRP; g++)
                if (!((gmask >> g) & 1) && gsc[g] > best) { best = gsc[g]; bi = g; }
            gmask |= 1 << bi;
        }
        for (int i = 0; i < NE; i++)
            smm[i] = ((gmask >> (i >> 2)) & 1) ? scb[i] : -1e30f;
        int ids[TOPK]; float wv[TOPK]; float wsum = 0.f;
        for (int k = 0; k < TOPK; k++) {
            float best = -1e31f; int bi = 0;
            for (int i = 0; i < NE; i++)
                if (smm[i] > best) { best = smm[i]; bi = i; }
            smm[bi] = -1e32f;
            ids[k] = bi; wv[k] = ss[bi]; wsum += ss[bi];
        }
        float inv = SCALE / wsum;
        for (int k = 0; k < TOPK; k++) {
            int ee = ids[k];
            int pos = atomicAdd(&counts[ee], 1);
            tok_ids[ee * T_TOK + pos] = t;
            tok_w[ee * T_TOK + pos] = wv[k] * inv;
            slotmap[t * TOPK + k] = (ee << 9) | pos;
        }
    }
}

__global__ void k_scan(const int* __restrict__ counts, int* __restrict__ offs) {
    if (threadIdx.x == 0) {
        int o = 0;
        for (int e = 0; e < NE; e++) { offs[e] = o; o += counts[e]; }
    }
}

// ---- gate_up: single-buf A + double-buf B, counted vmcnt, 4 blocks/CU -----
__global__ __launch_bounds__(256, 4) void k_gemm1(
    const float* __restrict__ wgu, const float* __restrict__ wsgu,
    const u16* __restrict__ xb,
    const int* __restrict__ counts, const int* __restrict__ offs,
    const int* __restrict__ tok_ids, const float* __restrict__ tok_w,
    u16* __restrict__ act) {
    const int tid = threadIdx.x, lane = tid & 63, w = tid >> 6;
    const int nb = blockIdx.x, mt = blockIdx.y, e = blockIdx.z;
    int ne, base, NS, upo; const float* gp;
    if (e < NE) {
        ne = counts[e]; base = offs[e];
        gp = wgu + (size_t)e * (HD * 2 * ID) + nb * 64;
        NS = 2 * ID; upo = ID;
    } else {
        int s = e - NE; ne = T_TOK; base = T_TOK * TOPK + s * T_TOK;
        gp = wsgu + s * ID + nb * 64;
        NS = 2 * NSH * ID; upo = NSH * ID;
    }
    if (mt * 128 >= ne) return;

    __shared__ __align__(16) u16   Al[4096];      // 8 KB (single buffer)
    __shared__ __align__(16) float Bl[2][4096];   // 16 KB x2

    const int c0 = 2 * w, c1 = 2 * w + 1;
    int sl0 = mt*128 + c0*16 + (lane & 15); if (sl0 > ne-1) sl0 = ne-1;
    int sl1 = mt*128 + c1*16 + (lane & 15); if (sl1 > ne-1) sl1 = ne-1;
    const int t0 = (e < NE) ? tok_ids[e*T_TOK + sl0] : sl0;
    const int t1 = (e < NE) ? tok_ids[e*T_TOK + sl1] : sl1;
    const char* a0 = (const char*)xb + (u32)t0 * (HD*2) + (lane >> 4) * 16;
    const char* a1 = (const char*)xb + (u32)t1 * (HD*2) + (lane >> 4) * 16;

    const float* bsrc[4];
#pragma unroll
    for (int i = 0; i < 4; i++) {
        int kloc = 8*w + 2*i + (lane >> 5);
        int c4 = (4 * (lane & 31)) ^ (((kloc >> 2) & 7) << 4);
        const float* bp = (c4 < 64) ? (gp + c4) : (gp + upo + (c4 - 64));
        bsrc[i] = bp + (size_t)kloc * NS;
    }
    const size_t kstep = (size_t)32 * NS;

    auto stageA = [&](int kt) {   // 2 glds per wave (L2-hot xb)
        glds16(a0 + (u32)kt * 64, &Al[c0 * 512]);
        glds16(a1 + (u32)kt * 64, &Al[c1 * 512]);
    };
    auto stageB = [&](int buf, int kt) {   // 4 glds per wave (HBM weights)
#pragma unroll
        for (int i = 0; i < 4; i++)
            glds16(bsrc[i] + (size_t)kt * kstep, &Bl[buf][(8*w + 2*i) * 128]);
    };

    f32x4 accg[8], accu[8];
#pragma unroll
    for (int f = 0; f < 8; f++) {
        accg[f] = (f32x4){0.f,0.f,0.f,0.f};
        accu[f] = (f32x4){0.f,0.f,0.f,0.f};
    }

    const int cg = w * 16 + (lane & 15);   // gate tile-col 0..63
    const int g  = lane >> 4;

    stageA(0);          // A(0): 2 glds
    stageB(0, 0);       // B(0): 4 glds
    int buf = 0;
    for (int kt = 0; kt < KT1; kt++) {
        if (kt + 1 < KT1) {
            stageB(buf ^ 1, kt + 1);                      // B prefetch in flight
            asm volatile("s_waitcnt vmcnt(4)" ::: "memory");  // A(kt)+B(kt) landed
        } else {
            asm volatile("s_waitcnt vmcnt(0)" ::: "memory");
        }
        __builtin_amdgcn_s_barrier();                     // tile kt landed (all waves)
        Q qg, qu;
        qg.v = bfrag(Bl[buf], cg, g);
        qu.v = bfrag(Bl[buf], cg + 64, g);
#pragma unroll
        for (int f = 0; f < 8; f++) {
            Q qa;
            qa.q = *(const uint4*)&Al[f * 512 + (lane >> 4) * 128 + (lane & 15) * 8];
            accg[f] = mfma16(qa.v, qg.v, accg[f]);
            accu[f] = mfma16(qa.v, qu.v, accu[f]);
        }
        __builtin_amdgcn_s_barrier();                     // reads done before re-stage
        if (kt + 1 < KT1) stageA(kt + 1);                 // A(kt+1) into single buf
        buf ^= 1;
    }

    // epilogue: silu(g)*u*cw -> frag-permuted act rows
    const int icol = nb * 64 + w * 16 + (lane & 15);
    const int kt2 = icol >> 5, r = icol & 31;
    const int pos = kt2 * 32 + ((r & 16) ? (((r & 15) >> 2) * 8 + 4 + (r & 3))
                                         : ((r >> 2) * 8 + (r & 3)));
#pragma unroll
    for (int f = 0; f < 8; f++) {
#pragma unroll
        for (int j = 0; j < 4; j++) {
            int slot = mt * 128 + f * 16 + (lane >> 4) * 4 + j;
            if (slot < ne) {
                float cw = (e < NE) ? tok_w[e * T_TOK + slot] : 1.f;
                float gg = accg[f][j], uu = accu[f][j];
                float vv = gg / (1.f + __expf(-gg)) * uu * cw;
                act[(size_t)(base + slot) * ID + pos] = f2bf(vv);
            }
        }
    }
}

// ---- down-proj: single-buf A + double-buf B, plain partial stores ---------
__global__ __launch_bounds__(256, 4) void k_gemm2(
    const float* __restrict__ wd, const float* __restrict__ wsd,
    const u16* __restrict__ act,
    const int* __restrict__ counts, const int* __restrict__ offs,
    float* __restrict__ part) {
    const int tid = threadIdx.x, lane = tid & 63, w = tid >> 6;
    const int nb = blockIdx.x, mt = blockIdx.y, e = blockIdx.z;
    int ne, base; const float* gp;
    if (e < NE) {
        ne = counts[e]; base = offs[e];
        gp = wd + (size_t)e * (ID * HD) + nb * 128;
    } else {
        int s = e - NE; ne = T_TOK; base = T_TOK * TOPK + s * T_TOK;
        gp = wsd + (size_t)s * (ID * HD) + nb * 128;
    }
    if (mt * 128 >= ne) return;
    const int NS = HD;

    __shared__ __align__(16) u16   Al[4096];
    __shared__ __align__(16) float Bl[2][4096];

    const int c0 = 2 * w, c1 = 2 * w + 1;
    int sl0 = mt*128 + c0*16 + (lane & 15); if (sl0 > ne-1) sl0 = ne-1;
    int sl1 = mt*128 + c1*16 + (lane & 15); if (sl1 > ne-1) sl1 = ne-1;
    const char* a0 = (const char*)act + (size_t)(base + sl0) * (ID*2) + (lane >> 4) * 16;
    const char* a1 = (const char*)act + (size_t)(base + sl1) * (ID*2) + (lane >> 4) * 16;

    const float* bsrc[4];
#pragma unroll
    for (int i = 0; i < 4; i++) {
        int kloc = 8*w + 2*i + (lane >> 5);
        int c4 = (4 * (lane & 31)) ^ (((kloc >> 2) & 7) << 4);
        bsrc[i] = gp + (size_t)kloc * NS + c4;
    }
    const size_t kstep = (size_t)32 * NS;

    auto stageA = [&](int kt) {
        glds16(a0 + (u32)kt * 64, &Al[c0 * 512]);
        glds16(a1 + (u32)kt * 64, &Al[c1 * 512]);
    };
    auto stageB = [&](int buf, int kt) {
#pragma unroll
        for (int i = 0; i < 4; i++)
            glds16(bsrc[i] + (size_t)kt * kstep, &Bl[buf][(8*w + 2*i) * 128]);
    };

    f32x4 acc[8][2];
#pragma unroll
    for (int f = 0; f < 8; f++) {
        acc[f][0] = (f32x4){0.f,0.f,0.f,0.f};
        acc[f][1] = (f32x4){0.f,0.f,0.f,0.f};
    }

    const int cA = w * 16 + (lane & 15);
    const int g  = lane >> 4;

    stageA(0);
    stageB(0, 0);
    int buf = 0;
    for (int kt = 0; kt < KT2; kt++) {
        if (kt + 1 < KT2) {
            stageB(buf ^ 1, kt + 1);
            asm volatile("s_waitcnt vmcnt(4)" ::: "memory");
        } else {
            asm volatile("s_waitcnt vmcnt(0)" ::: "memory");
        }
        __builtin_amdgcn_s_barrier();
        Q q0, q1;
        q0.v = bfrag(Bl[buf], cA, g);
        q1.v = bfrag(Bl[buf], cA + 64, g);
#pragma unroll
        for (int f = 0; f < 8; f++) {
            Q qa;
            qa.q = *(const uint4*)&Al[f * 512 + (lane >> 4) * 128 + (lane & 15) * 8];
            acc[f][0] = mfma16(qa.v, q0.v, acc[f][0]);
            acc[f][1] = mfma16(qa.v, q1.v, acc[f][1]);
        }
        __builtin_amdgcn_s_barrier();
        if (kt + 1 < KT2) stageA(kt + 1);
        buf ^= 1;
    }

    const int col0 = nb * 128 + w * 16 + (lane & 15);
#pragma unroll
    for (int f = 0; f < 8; f++) {
#pragma unroll
        for (int j = 0; j < 4; j++) {
            int slot = mt * 128 + f * 16 + (lane >> 4) * 4 + j;
            if (slot < ne) {
                float* pr = part + (size_t)(base + slot) * HD + col0;
                pr[0]  = acc[f][0][j];
                pr[64] = acc[f][1][j];
            }
        }
    }
}

// ---------------- combine: out[t] = sum of 8 routed + 2 shared partials ----
__global__ __launch_bounds__(256) void k_combine(const float* __restrict__ part,
                                                 const int* __restrict__ offs,
                                                 const int* __restrict__ slotmap,
                                                 float* __restrict__ out) {
    const int t = blockIdx.x, tid = threadIdx.x;
    __shared__ int rows[16];
    if (tid < TOPK) {
        int pk = slotmap[t * TOPK + tid];
        rows[tid] = offs[pk >> 9] + (pk & 511);
    } else if (tid < TOPK + NSH) {
        rows[tid] = T_TOK * TOPK + (tid - TOPK) * T_TOK + t;
    }
    __syncthreads();
    float4 s0 = {0,0,0,0}, s1 = {0,0,0,0};
#pragma unroll
    for (int k = 0; k < TOPK + NSH; k++) {
        const float* p = part + (size_t)rows[k] * HD + tid * 8;
        float4 a = ((const float4*)p)[0], b = ((const float4*)p)[1];
        s0.x += a.x; s0.y += a.y; s0.z += a.z; s0.w += a.w;
        s1.x += b.x; s1.y += b.y; s1.z += b.z; s1.w += b.w;
    }
    float* o = out + (size_t)t * HD + tid * 8;
    ((float4*)o)[0] = s0;
    ((float4*)o)[1] = s1;
}

// ---------------- launcher ----------------
extern "C" void kernel_launch(void* const* d_in, const int* in_sizes, int n_in,
                              void* d_out, int out_size, void* d_ws, size_t ws_size,
                              hipStream_t stream) {
    const float* x    = (const float*)d_in[0];
    const float* gw   = (const float*)d_in[1];
    const float* gb   = (const float*)d_in[2];
    const float* wgu  = (const float*)d_in[3];
    const float* wd   = (const float*)d_in[4];
    const float* wsgu = (const float*)d_in[5];
    const float* wsd  = (const float*)d_in[6];
    float* out = (float*)d_out;

    char* wsb = (char*)d_ws;
    int*   counts  = (int*)(wsb);                  // 128 B
    int*   offs    = (int*)(wsb + 128);            // 128 B
    int*   tok_ids = (int*)(wsb + 256);            // 64 KB
    float* tok_w   = (float*)(wsb + 65792);        // 64 KB
    int*   slotmap = (int*)(wsb + 131328);         // 16 KB
    u16*   xb      = (u16*)(wsb + 147712);         // 2 MB (frag-permuted)
    u16*   act     = (u16*)(wsb + 2244864);        // 10 MB (frag-permuted)
    float* part    = (float*)(wsb + 12730624);     // 40 MB (5120 x 2048 fp32)

    hipMemsetAsync(counts, 0, 128, stream);
    k_xconv<<<dim3((T_TOK * 64) / 256), 256, 0, stream>>>(x, xb);
    k_route<<<dim3(T_TOK), 64, 0, stream>>>(x, gw, gb, counts, tok_ids, tok_w, slotmap);
    k_scan<<<dim3(1), 64, 0, stream>>>(counts, offs);
    k_gemm1<<<dim3(ID / 64, 4, NEXP), 256, 0, stream>>>(
        wgu, wsgu, xb, counts, offs, tok_ids, tok_w, act);
    k_gemm2<<<dim3(HD / 128, 4, NEXP), 256, 0, stream>>>(
        wd, wsd, act, counts, offs, part);
    k_combine<<<dim3(T_TOK), 256, 0, stream>>>(part, offs, slotmap, out);
}

// Round 15
// 382.178 us; speedup vs baseline: 1.8082x; 1.0217x over previous
//
#include <hip/hip_runtime.h>
#include <hip/hip_bf16.h>

// ---------------- problem constants ----------------
#define T_TOK 512
#define HD    2048   // hidden
#define ID    1024   // moe intermediate
#define NE    32     // routed experts
#define TOPK  8
#define NGRP  8
#define TGRP  4
#define NSH   2
#define SCALE 2.5f
#define NEXP  (NE + NSH)
#define KT1   64     // HD/32
#define KT2   32     // ID/32

typedef __attribute__((ext_vector_type(8))) short bf16x8;
typedef __attribute__((ext_vector_type(4))) float f32x4;
typedef unsigned short u16;
typedef unsigned long long u64;
typedef unsigned int u32;

__device__ __forceinline__ u16 f2bf(float f) {
    union { float f; u32 u; } a; a.f = f;
    u32 r = a.u + 0x7FFFu + ((a.u >> 16) & 1u);   // RNE
    return (u16)(r >> 16);
}

__device__ __forceinline__ float bf2f(u16 h) {
    union { u32 u; float f; } z; z.u = (u32)h << 16; return z.f;
}

// pack two fp32 -> dword of 2 bf16 (lo in low half), RNE
__device__ __forceinline__ u32 pk2(float lo, float hi) {
    union { float f; u32 u; } a, b; a.f = lo; b.f = hi;
    u32 rl = a.u + 0x7FFFu + ((a.u >> 16) & 1u);
    u32 rh = b.u + 0x7FFFu + ((b.u >> 16) & 1u);
    return (rh & 0xFFFF0000u) | (rl >> 16);
}

__device__ __forceinline__ f32x4 mfma16(bf16x8 a, bf16x8 b, f32x4 c) {
    return __builtin_amdgcn_mfma_f32_16x16x32_bf16(a, b, c, 0, 0, 0);
}

union Q { uint4 q; bf16x8 v; };

// async global->LDS, 16B per lane
__device__ __forceinline__ void glds16(const void* g, void* l) {
    __builtin_amdgcn_global_load_lds(
        (const __attribute__((address_space(1))) u32*)g,
        (__attribute__((address_space(3))) u32*)l, 16, 0, 0);
}

// build B fragment from swizzled fp32 LDS tile [32k][128c] (verified r6-r14)
__device__ __forceinline__ bf16x8 bfrag(const float* Bt, int c, int g) {
    const int clo = c ^ (g << 4);
    const float* p_lo = Bt + g * 512 + clo;               // k = 4g + {0..3}
    const float* p_hi = Bt + g * 512 + 2048 + (clo ^ 64); // k = 4g+16+{0..3}
    union { u32 d[4]; bf16x8 v; } r;
    r.d[0] = pk2(p_lo[0],   p_lo[128]);
    r.d[1] = pk2(p_lo[256], p_lo[384]);
    r.d[2] = pk2(p_hi[0],   p_hi[128]);
    r.d[3] = pk2(p_hi[256], p_hi[384]);
    return r.v;
}

// ---------------- routing + fused x->bf16 frag-permuted conversion ---------
__global__ __launch_bounds__(64) void k_route(const float* __restrict__ x,
                                              const float* __restrict__ gw,
                                              const float* __restrict__ gb,
                                              int* __restrict__ counts,
                                              int* __restrict__ tok_ids,
                                              float* __restrict__ tok_w,
                                              int* __restrict__ slotmap,
                                              u16* __restrict__ xb) {
    const int t = blockIdx.x, lane = threadIdx.x;
    __shared__ float xr[HD];
    __shared__ float slog[NE], ss[NE], scb[NE], smm[NE];
    for (int i = lane; i < HD; i += 64) xr[i] = x[(size_t)t * HD + i];
    __syncthreads();
    const int e = lane >> 1, half = lane & 1;
    const float4* w4 = (const float4*)(gw + (size_t)e * HD + half * 1024);
    const float4* x4 = (const float4*)(xr + half * 1024);
    float acc = 0.f;
#pragma unroll 8
    for (int i = 0; i < 256; i++) {
        float4 a = x4[i], b = w4[i];
        acc += a.x * b.x + a.y * b.y + a.z * b.z + a.w * b.w;
    }
    acc += __shfl_xor(acc, 1, 64);
    if (!half) slog[e] = acc;
    __syncthreads();
    {   // fused xconv: lane = kt tile, frag-permuted bf16 row (r4-r14 layout)
        const float* src = xr + lane * 32;
        union { u16 o[32]; uint4 q[4]; } pk;
#pragma unroll
        for (int g = 0; g < 4; g++)
#pragma unroll
            for (int jj = 0; jj < 8; jj++) {
                int r = (jj < 4) ? 4*g + jj : 4*g + 16 + (jj - 4);
                pk.o[g*8 + jj] = f2bf(src[r]);
            }
        uint4* d = (uint4*)(xb + (size_t)t * HD + lane * 32);
#pragma unroll
        for (int i = 0; i < 4; i++) d[i] = pk.q[i];
    }
    if (lane == 0) {
        for (int i = 0; i < NE; i++) {
            float s = 1.f / (1.f + __expf(-slog[i]));
            ss[i] = s; scb[i] = s + gb[i];
        }
        float gsc[NGRP];
        for (int g = 0; g < NGRP; g++) {
            float a = scb[4*g], b = scb[4*g+1], c = scb[4*g+2], d = scb[4*g+3];
            float mab = fmaxf(a,b), nab = fminf(a,b), mcd = fmaxf(c,d), ncd = fminf(c,d);
            float m2 = (mab >= mcd) ? fmaxf(nab, mcd) : fmaxf(ncd, mab);
            gsc[g] = fmaxf(mab, mcd) + m2;
        }
        int gmask = 0;
        for (int it = 0; it < TGRP; it++) {
            float best = -1e30f; int bi = 0;
            for (int g = 0; g < NGRP; g++)
                if (!((gmask >> g) & 1) && gsc[g] > best) { best = gsc[g]; bi = g; }
            gmask |= 1 << bi;
        }
        for (int i = 0; i < NE; i++)
            smm[i] = ((gmask >> (i >> 2)) & 1) ? scb[i] : -1e30f;
        int ids[TOPK]; float wv[TOPK]; float wsum = 0.f;
        for (int k = 0; k < TOPK; k++) {
            float best = -1e31f; int bi = 0;
            for (int i = 0; i < NE; i++)
                if (smm[i] > best) { best = smm[i]; bi = i; }
            smm[bi] = -1e32f;
            ids[k] = bi; wv[k] = ss[bi]; wsum += ss[bi];
        }
        float inv = SCALE / wsum;
        for (int k = 0; k < TOPK; k++) {
            int ee = ids[k];
            int pos = atomicAdd(&counts[ee], 1);
            tok_ids[ee * T_TOK + pos] = t;
            tok_w[ee * T_TOK + pos] = wv[k] * inv;
            slotmap[t * TOPK + k] = (ee << 9) | pos;
        }
    }
}

__global__ void k_scan(const int* __restrict__ counts, int* __restrict__ offs) {
    if (threadIdx.x == 0) {
        int o = 0;
        for (int e = 0; e < NE; e++) { offs[e] = o; o += counts[e]; }
    }
}

// ---- gate_up: single-buf A + double-buf B, counted vmcnt, 4 blocks/CU -----
__global__ __launch_bounds__(256, 4) void k_gemm1(
    const float* __restrict__ wgu, const float* __restrict__ wsgu,
    const u16* __restrict__ xb,
    const int* __restrict__ counts, const int* __restrict__ offs,
    const int* __restrict__ tok_ids, const float* __restrict__ tok_w,
    u16* __restrict__ act) {
    const int tid = threadIdx.x, lane = tid & 63, w = tid >> 6;
    const int nb = blockIdx.x, mt = blockIdx.y, e = blockIdx.z;
    int ne, base, NS, upo; const float* gp;
    if (e < NE) {
        ne = counts[e]; base = offs[e];
        gp = wgu + (size_t)e * (HD * 2 * ID) + nb * 64;
        NS = 2 * ID; upo = ID;
    } else {
        int s = e - NE; ne = T_TOK; base = T_TOK * TOPK + s * T_TOK;
        gp = wsgu + s * ID + nb * 64;
        NS = 2 * NSH * ID; upo = NSH * ID;
    }
    if (mt * 128 >= ne) return;

    __shared__ __align__(16) u16   Al[4096];      // 8 KB (single buffer)
    __shared__ __align__(16) float Bl[2][4096];   // 16 KB x2

    const int c0 = 2 * w, c1 = 2 * w + 1;
    int sl0 = mt*128 + c0*16 + (lane & 15); if (sl0 > ne-1) sl0 = ne-1;
    int sl1 = mt*128 + c1*16 + (lane & 15); if (sl1 > ne-1) sl1 = ne-1;
    const int t0 = (e < NE) ? tok_ids[e*T_TOK + sl0] : sl0;
    const int t1 = (e < NE) ? tok_ids[e*T_TOK + sl1] : sl1;
    const char* a0 = (const char*)xb + (u32)t0 * (HD*2) + (lane >> 4) * 16;
    const char* a1 = (const char*)xb + (u32)t1 * (HD*2) + (lane >> 4) * 16;

    const float* bsrc[4];
#pragma unroll
    for (int i = 0; i < 4; i++) {
        int kloc = 8*w + 2*i + (lane >> 5);
        int c4 = (4 * (lane & 31)) ^ (((kloc >> 2) & 7) << 4);
        const float* bp = (c4 < 64) ? (gp + c4) : (gp + upo + (c4 - 64));
        bsrc[i] = bp + (size_t)kloc * NS;
    }
    const size_t kstep = (size_t)32 * NS;

    auto stageA = [&](int kt) {   // 2 glds per wave (L2-hot xb)
        glds16(a0 + (u32)kt * 64, &Al[c0 * 512]);
        glds16(a1 + (u32)kt * 64, &Al[c1 * 512]);
    };
    auto stageB = [&](int buf, int kt) {   // 4 glds per wave (HBM weights)
#pragma unroll
        for (int i = 0; i < 4; i++)
            glds16(bsrc[i] + (size_t)kt * kstep, &Bl[buf][(8*w + 2*i) * 128]);
    };

    f32x4 accg[8], accu[8];
#pragma unroll
    for (int f = 0; f < 8; f++) {
        accg[f] = (f32x4){0.f,0.f,0.f,0.f};
        accu[f] = (f32x4){0.f,0.f,0.f,0.f};
    }

    const int cg = w * 16 + (lane & 15);   // gate tile-col 0..63
    const int g  = lane >> 4;

    stageA(0);          // A(0): 2 glds
    stageB(0, 0);       // B(0): 4 glds
    int buf = 0;
    for (int kt = 0; kt < KT1; kt++) {
        if (kt + 1 < KT1) {
            stageB(buf ^ 1, kt + 1);                      // B prefetch in flight
            asm volatile("s_waitcnt vmcnt(4)" ::: "memory");  // A(kt)+B(kt) landed
        } else {
            asm volatile("s_waitcnt vmcnt(0)" ::: "memory");
        }
        __builtin_amdgcn_s_barrier();                     // tile kt landed (all waves)
        Q qg, qu;
        qg.v = bfrag(Bl[buf], cg, g);
        qu.v = bfrag(Bl[buf], cg + 64, g);
#pragma unroll
        for (int f = 0; f < 8; f++) {
            Q qa;
            qa.q = *(const uint4*)&Al[f * 512 + (lane >> 4) * 128 + (lane & 15) * 8];
            accg[f] = mfma16(qa.v, qg.v, accg[f]);
            accu[f] = mfma16(qa.v, qu.v, accu[f]);
        }
        __builtin_amdgcn_s_barrier();                     // reads done before re-stage
        if (kt + 1 < KT1) stageA(kt + 1);                 // A(kt+1) into single buf
        buf ^= 1;
    }

    // epilogue: silu(g)*u*cw -> frag-permuted act rows
    const int icol = nb * 64 + w * 16 + (lane & 15);
    const int kt2 = icol >> 5, r = icol & 31;
    const int pos = kt2 * 32 + ((r & 16) ? (((r & 15) >> 2) * 8 + 4 + (r & 3))
                                         : ((r >> 2) * 8 + (r & 3)));
#pragma unroll
    for (int f = 0; f < 8; f++) {
#pragma unroll
        for (int j = 0; j < 4; j++) {
            int slot = mt * 128 + f * 16 + (lane >> 4) * 4 + j;
            if (slot < ne) {
                float cw = (e < NE) ? tok_w[e * T_TOK + slot] : 1.f;
                float gg = accg[f][j], uu = accu[f][j];
                float vv = gg / (1.f + __expf(-gg)) * uu * cw;
                act[(size_t)(base + slot) * ID + pos] = f2bf(vv);
            }
        }
    }
}

// ---- down-proj: single-buf A + double-buf B, bf16 partial stores ----------
__global__ __launch_bounds__(256, 4) void k_gemm2(
    const float* __restrict__ wd, const float* __restrict__ wsd,
    const u16* __restrict__ act,
    const int* __restrict__ counts, const int* __restrict__ offs,
    u16* __restrict__ part) {
    const int tid = threadIdx.x, lane = tid & 63, w = tid >> 6;
    const int nb = blockIdx.x, mt = blockIdx.y, e = blockIdx.z;
    int ne, base; const float* gp;
    if (e < NE) {
        ne = counts[e]; base = offs[e];
        gp = wd + (size_t)e * (ID * HD) + nb * 128;
    } else {
        int s = e - NE; ne = T_TOK; base = T_TOK * TOPK + s * T_TOK;
        gp = wsd + (size_t)s * (ID * HD) + nb * 128;
    }
    if (mt * 128 >= ne) return;
    const int NS = HD;

    __shared__ __align__(16) u16   Al[4096];
    __shared__ __align__(16) float Bl[2][4096];

    const int c0 = 2 * w, c1 = 2 * w + 1;
    int sl0 = mt*128 + c0*16 + (lane & 15); if (sl0 > ne-1) sl0 = ne-1;
    int sl1 = mt*128 + c1*16 + (lane & 15); if (sl1 > ne-1) sl1 = ne-1;
    const char* a0 = (const char*)act + (size_t)(base + sl0) * (ID*2) + (lane >> 4) * 16;
    const char* a1 = (const char*)act + (size_t)(base + sl1) * (ID*2) + (lane >> 4) * 16;

    const float* bsrc[4];
#pragma unroll
    for (int i = 0; i < 4; i++) {
        int kloc = 8*w + 2*i + (lane >> 5);
        int c4 = (4 * (lane & 31)) ^ (((kloc >> 2) & 7) << 4);
        bsrc[i] = gp + (size_t)kloc * NS + c4;
    }
    const size_t kstep = (size_t)32 * NS;

    auto stageA = [&](int kt) {
        glds16(a0 + (u32)kt * 64, &Al[c0 * 512]);
        glds16(a1 + (u32)kt * 64, &Al[c1 * 512]);
    };
    auto stageB = [&](int buf, int kt) {
#pragma unroll
        for (int i = 0; i < 4; i++)
            glds16(bsrc[i] + (size_t)kt * kstep, &Bl[buf][(8*w + 2*i) * 128]);
    };

    f32x4 acc[8][2];
#pragma unroll
    for (int f = 0; f < 8; f++) {
        acc[f][0] = (f32x4){0.f,0.f,0.f,0.f};
        acc[f][1] = (f32x4){0.f,0.f,0.f,0.f};
    }

    const int cA = w * 16 + (lane & 15);
    const int g  = lane >> 4;

    stageA(0);
    stageB(0, 0);
    int buf = 0;
    for (int kt = 0; kt < KT2; kt++) {
        if (kt + 1 < KT2) {
            stageB(buf ^ 1, kt + 1);
            asm volatile("s_waitcnt vmcnt(4)" ::: "memory");
        } else {
            asm volatile("s_waitcnt vmcnt(0)" ::: "memory");
        }
        __builtin_amdgcn_s_barrier();
        Q q0, q1;
        q0.v = bfrag(Bl[buf], cA, g);
        q1.v = bfrag(Bl[buf], cA + 64, g);
#pragma unroll
        for (int f = 0; f < 8; f++) {
            Q qa;
            qa.q = *(const uint4*)&Al[f * 512 + (lane >> 4) * 128 + (lane & 15) * 8];
            acc[f][0] = mfma16(qa.v, q0.v, acc[f][0]);
            acc[f][1] = mfma16(qa.v, q1.v, acc[f][1]);
        }
        __builtin_amdgcn_s_barrier();
        if (kt + 1 < KT2) stageA(kt + 1);
        buf ^= 1;
    }

    const int col0 = nb * 128 + w * 16 + (lane & 15);
#pragma unroll
    for (int f = 0; f < 8; f++) {
#pragma unroll
        for (int j = 0; j < 4; j++) {
            int slot = mt * 128 + f * 16 + (lane >> 4) * 4 + j;
            if (slot < ne) {
                u16* pr = part + (size_t)(base + slot) * HD + col0;
                pr[0]  = f2bf(acc[f][0][j]);
                pr[64] = f2bf(acc[f][1][j]);
            }
        }
    }
}

// ---------------- combine: out[t] = sum of 8 routed + 2 shared partials ----
__global__ __launch_bounds__(256) void k_combine(const u16* __restrict__ part,
                                                 const int* __restrict__ offs,
                                                 const int* __restrict__ slotmap,
                                                 float* __restrict__ out) {
    const int t = blockIdx.x, tid = threadIdx.x;
    __shared__ int rows[16];
    if (tid < TOPK) {
        int pk = slotmap[t * TOPK + tid];
        rows[tid] = offs[pk >> 9] + (pk & 511);
    } else if (tid < TOPK + NSH) {
        rows[tid] = T_TOK * TOPK + (tid - TOPK) * T_TOK + t;
    }
    __syncthreads();
    float s[8] = {0,0,0,0,0,0,0,0};
#pragma unroll
    for (int k = 0; k < TOPK + NSH; k++) {
        const u16* p = part + (size_t)rows[k] * HD + tid * 8;
        union { uint4 q; u16 u[8]; } r;
        r.q = *(const uint4*)p;
#pragma unroll
        for (int j = 0; j < 8; j++) s[j] += bf2f(r.u[j]);
    }
    float* o = out + (size_t)t * HD + tid * 8;
    float4 s0 = {s[0], s[1], s[2], s[3]};
    float4 s1 = {s[4], s[5], s[6], s[7]};
    ((float4*)o)[0] = s0;
    ((float4*)o)[1] = s1;
}

// ---------------- launcher ----------------
extern "C" void kernel_launch(void* const* d_in, const int* in_sizes, int n_in,
                              void* d_out, int out_size, void* d_ws, size_t ws_size,
                              hipStream_t stream) {
    const float* x    = (const float*)d_in[0];
    const float* gw   = (const float*)d_in[1];
    const float* gb   = (const float*)d_in[2];
    const float* wgu  = (const float*)d_in[3];
    const float* wd   = (const float*)d_in[4];
    const float* wsgu = (const float*)d_in[5];
    const float* wsd  = (const float*)d_in[6];
    float* out = (float*)d_out;

    char* wsb = (char*)d_ws;
    int*   counts  = (int*)(wsb);                  // 128 B
    int*   offs    = (int*)(wsb + 128);            // 128 B
    int*   tok_ids = (int*)(wsb + 256);            // 64 KB
    float* tok_w   = (float*)(wsb + 65792);        // 64 KB
    int*   slotmap = (int*)(wsb + 131328);         // 16 KB
    u16*   xb      = (u16*)(wsb + 147712);         // 2 MB (frag-permuted)
    u16*   act     = (u16*)(wsb + 2244864);        // 10 MB (frag-permuted)
    u16*   part    = (u16*)(wsb + 12730624);       // 20 MB (5120 x 2048 bf16)

    hipMemsetAsync(counts, 0, 128, stream);
    k_route<<<dim3(T_TOK), 64, 0, stream>>>(x, gw, gb, counts, tok_ids, tok_w,
                                            slotmap, xb);
    k_scan<<<dim3(1), 64, 0, stream>>>(counts, offs);
    k_gemm1<<<dim3(ID / 64, 4, NEXP), 256, 0, stream>>>(
        wgu, wsgu, xb, counts, offs, tok_ids, tok_w, act);
    k_gemm2<<<dim3(HD / 128, 4, NEXP), 256, 0, stream>>>(
        wd, wsd, act, counts, offs, part);
    k_combine<<<dim3(T_TOK), 256, 0, stream>>>(part, offs, slotmap, out);
}